// Round 9
// baseline (186.686 us; speedup 1.0000x reference)
//
#include <hip/hip_runtime.h>
#include <math.h>

#define N 512
#define NPAD(i) ((i) + ((i) >> 5))
#define FSZ 532
#define NCOL 257           // Hermitian: columns v = 0..256 only
// mask: (u-256)^2 + (v-256)^2 <= 51.2^2 (integer dist^2 exact in fp32)
#define RAD2 2621.44f
#define SQ2H 0.70710678f

// ---------------------------------------------------------------------------
// In-register 8-point DFT, natural order in/out.
// ---------------------------------------------------------------------------
__device__ __forceinline__ void dft8(float (&xr)[8], float (&xi)[8]) {
    float e0r = xr[0] + xr[4], e0i = xi[0] + xi[4];
    float e1r = xr[0] - xr[4], e1i = xi[0] - xi[4];
    float e2r = xr[2] + xr[6], e2i = xi[2] + xi[6];
    float e3r = xr[2] - xr[6], e3i = xi[2] - xi[6];
    float E0r = e0r + e2r, E0i = e0i + e2i;
    float E2r = e0r - e2r, E2i = e0i - e2i;
    float E1r = e1r + e3i, E1i = e1i - e3r;
    float E3r = e1r - e3i, E3i = e1i + e3r;
    float o0r = xr[1] + xr[5], o0i = xi[1] + xi[5];
    float o1r = xr[1] - xr[5], o1i = xi[1] - xi[5];
    float o2r = xr[3] + xr[7], o2i = xi[3] + xi[7];
    float o3r = xr[3] - xr[7], o3i = xi[3] - xi[7];
    float O0r = o0r + o2r, O0i = o0i + o2i;
    float O2r = o0r - o2r, O2i = o0i - o2i;
    float O1r = o1r + o3i, O1i = o1i - o3r;
    float O3r = o1r - o3i, O3i = o1i + o3r;
    float t1r = SQ2H * (O1r + O1i), t1i = SQ2H * (O1i - O1r);
    float t2r = O2i,                t2i = -O2r;
    float t3r = SQ2H * (O3i - O3r), t3i = -SQ2H * (O3r + O3i);
    xr[0] = E0r + O0r; xi[0] = E0i + O0i;
    xr[4] = E0r - O0r; xi[4] = E0i - O0i;
    xr[1] = E1r + t1r; xi[1] = E1i + t1i;
    xr[5] = E1r - t1r; xi[5] = E1i - t1i;
    xr[2] = E2r + t2r; xi[2] = E2i + t2i;
    xr[6] = E2r - t2r; xi[6] = E2i - t2i;
    xr[3] = E3r + t3r; xi[3] = E3i + t3i;
    xr[7] = E3r - t3r; xi[7] = E3i - t3i;
}

// ---------------------------------------------------------------------------
// TWO interleaved wave-level 512-pt FFTs. BATCHED SHUFFLES: all 32 ds ops of
// a stage are issued into temporaries before any consumer, so the wave keeps
// a deep outstanding-lgkm window instead of waiting per-pair.
// Lane l, reg k holds x[8*l + k] in; out: reg t holds X[br6(l) + 64*t].
// ---------------------------------------------------------------------------
__device__ __forceinline__ void fft512_x2(float (&ar)[8], float (&ai)[8],
                                          float (&br)[8], float (&bi)[8],
                                          int l) {
#pragma unroll
    for (int half = 32; half >= 1; half >>= 1) {
        const int j = l & (half - 1);
        const float f = (float)j * (0.5f / (float)half);   // revolutions
        const float c = __builtin_amdgcn_cosf(f);
        const float s = __builtin_amdgcn_sinf(f);
        const bool up = (l & half) != 0;
        const float sgn = up ? -1.0f : 1.0f;
        const float wc  = up ? c : 1.0f;
        const float ws  = up ? s : 0.0f;
        float par[8], pai[8], pbr[8], pbi[8];
#pragma unroll
        for (int k = 0; k < 8; ++k) {          // issue phase: 32 independent
            par[k] = __shfl_xor(ar[k], half);
            pai[k] = __shfl_xor(ai[k], half);
            pbr[k] = __shfl_xor(br[k], half);
            pbi[k] = __shfl_xor(bi[k], half);
        }
#pragma unroll
        for (int k = 0; k < 8; ++k) {          // consume phase: pure VALU
            float tr = fmaf(sgn, ar[k], par[k]);
            float ti = fmaf(sgn, ai[k], pai[k]);
            float ur = fmaf(sgn, br[k], pbr[k]);
            float ui = fmaf(sgn, bi[k], pbi[k]);
            ar[k] = tr * wc + ti * ws;
            ai[k] = ti * wc - tr * ws;
            br[k] = ur * wc + ui * ws;
            bi[k] = ui * wc - ur * ws;
        }
    }
    const int w = __brev((unsigned)l) >> 26;
#pragma unroll
    for (int k = 1; k < 8; ++k) {
        const float f = (float)(k * w) * (1.0f / 512.0f);
        const float c = __builtin_amdgcn_cosf(f);
        const float s = __builtin_amdgcn_sinf(f);
        float tr = ar[k] * c + ai[k] * s;
        float ti = ai[k] * c - ar[k] * s;
        ar[k] = tr; ai[k] = ti;
        float ur = br[k] * c + bi[k] * s;
        float ui = bi[k] * c - br[k] * s;
        br[k] = ur; bi[k] = ui;
    }
    dft8(ar, ai);
    dft8(br, bi);
}

// ---------------------------------------------------------------------------
// K1: grayscale + 2 packed row-pair FFTs per wave + Hermitian unpack +
// transposed write. 512 thr = 8 waves = 32 rows.
// ---------------------------------------------------------------------------
__global__ __launch_bounds__(512) void k_gray_rowfft(
    const float* __restrict__ img, float2* __restrict__ buf) {
    __shared__ float sr[16][FSZ], si[16][FSZ];
    const int t = threadIdx.x, wv = t >> 6, l = t & 63;
    const int b = blockIdx.y, tile = blockIdx.x;
    const size_t plane = (size_t)N * N;
    const float* base = img + (size_t)b * 3 * plane;
    const int r0 = tile * 32 + 4 * wv;

    const float inv3 = 1.0f / 3.0f;
    auto loadgray = [&](const float* p, float (&g)[8]) {
        const float4* c0 = (const float4*)p;
        const float4* c1 = (const float4*)(p + plane);
        const float4* c2 = (const float4*)(p + 2 * plane);
#pragma unroll
        for (int q = 0; q < 2; ++q) {
            float4 a = c0[2 * l + q], bb = c1[2 * l + q], c = c2[2 * l + q];
            g[4 * q + 0] = (a.x + bb.x + c.x) * inv3;
            g[4 * q + 1] = (a.y + bb.y + c.y) * inv3;
            g[4 * q + 2] = (a.z + bb.z + c.z) * inv3;
            g[4 * q + 3] = (a.w + bb.w + c.w) * inv3;
        }
    };

    float arr[8], ari[8], brr[8], bri[8];
    loadgray(base + (size_t)(r0 + 0) * N, arr);
    loadgray(base + (size_t)(r0 + 1) * N, ari);
    loadgray(base + (size_t)(r0 + 2) * N, brr);
    loadgray(base + (size_t)(r0 + 3) * N, bri);

    fft512_x2(arr, ari, brr, bri, l);

    const int w = __brev((unsigned)l) >> 26;
    const int sA = 2 * wv, sB = 2 * wv + 1;
#pragma unroll
    for (int k = 0; k < 8; ++k) {
        int u = w + 64 * k;
        sr[sA][NPAD(u)] = arr[k]; si[sA][NPAD(u)] = ari[k];
        sr[sB][NPAD(u)] = brr[k]; si[sB][NPAD(u)] = bri[k];
    }
    __syncthreads();

    const int p = t & 15;
    const int h2 = 2 * p;
    const int slot = t >> 4;
    float2* ob = buf + (size_t)b * NCOL * N;
#pragma unroll
    for (int it = 0; it < 9; ++it) {
        int v = slot + 32 * it;
        if (v < NCOL) {
            int vn = (N - v) & (N - 1);
            float Zr  = sr[p][NPAD(v)],  Zi  = si[p][NPAD(v)];
            float Zr2 = sr[p][NPAD(vn)], Zi2 = si[p][NPAD(vn)];
            float4 o;
            o.x = 0.5f * (Zr + Zr2);
            o.y = 0.5f * (Zi - Zi2);
            o.z = 0.5f * (Zi + Zi2);
            o.w = 0.5f * (Zr2 - Zr);
            *(float4*)(&ob[(size_t)v * N + tile * 32 + h2]) = o;
        }
    }
}

// ---------------------------------------------------------------------------
// K2: 2 column FFTs per wave + per-column masked/total partial sums.
// NO LDS, NO barriers, NO atomics: lane 0 stores part[b][v] per column.
// 256 thr = 4 waves = 8 columns.
// ---------------------------------------------------------------------------
__global__ __launch_bounds__(256) void k_colfft_reduce(
    const float2* __restrict__ buf, float2* __restrict__ part) {
    const int t = threadIdx.x, wv = t >> 6, l = t & 63;
    const int b = blockIdx.y;
    const int v0 = blockIdx.x * 8 + 2 * wv;
    const int v1 = v0 + 1;
    const int c0 = v0 > 256 ? 256 : v0;
    const int c1 = v1 > 256 ? 256 : v1;

    const float4* colA = (const float4*)(buf + ((size_t)b * NCOL + c0) * N);
    const float4* colB = (const float4*)(buf + ((size_t)b * NCOL + c1) * N);
    float arr[8], ari[8], brr[8], bri[8];
#pragma unroll
    for (int q = 0; q < 4; ++q) {
        float4 zA = colA[4 * l + q];
        float4 zB = colB[4 * l + q];
        arr[2 * q] = zA.x; ari[2 * q] = zA.y;
        arr[2 * q + 1] = zA.z; ari[2 * q + 1] = zA.w;
        brr[2 * q] = zB.x; bri[2 * q] = zB.y;
        brr[2 * q + 1] = zB.z; bri[2 * q + 1] = zB.w;
    }

    fft512_x2(arr, ari, brr, bri, l);

    const float wA = (v0 == 0 || v0 == 256) ? 1.0f : 2.0f;
    const float wB = (v1 == 256) ? 1.0f : 2.0f;
    const float dxA = (float)(c0 - 256), dxA2 = dxA * dxA;
    const float dxB = (float)(c1 - 256), dxB2 = dxB * dxB;
    const int w = __brev((unsigned)l) >> 26;
    float mA = 0.0f, tA = 0.0f, mB = 0.0f, tB = 0.0f;
#pragma unroll
    for (int k = 0; k < 8; ++k) {
        int u = w + 64 * k;
        float dy = (float)(u - 256);
        float dy2 = dy * dy;
        float magA = sqrtf(arr[k] * arr[k] + ari[k] * ari[k]);
        float magB = sqrtf(brr[k] * brr[k] + bri[k] * bri[k]);
        tA += magA; tB += magB;
        if (dy2 + dxA2 <= RAD2) mA += magA;
        if (dy2 + dxB2 <= RAD2) mB += magB;
    }
    // batched 4-value wave reduction
#pragma unroll
    for (int off = 32; off > 0; off >>= 1) {
        float r0 = __shfl_down(mA, off);
        float r1 = __shfl_down(tA, off);
        float r2 = __shfl_down(mB, off);
        float r3 = __shfl_down(tB, off);
        mA += r0; tA += r1; mB += r2; tB += r3;
    }
    if (l == 0) {
        if (v0 <= 256) part[b * NCOL + v0] = make_float2(mA * wA, tA * wA);
        if (v1 <= 256) part[b * NCOL + v1] = make_float2(mB * wB, tB * wB);
    }
}

// K3: per-image reduce of 257 column partials, then mean of ratios.
__global__ void k_final(const float2* __restrict__ part,
                        float* __restrict__ out) {
    int t = threadIdx.x;                       // 64 threads
    float r = 0.0f;
    if (t < 32) {
        float m = 0.0f, s = 0.0f;
        const float2* p = part + t * NCOL;
        for (int v = 0; v < NCOL; ++v) {
            float2 q = p[v];
            m += q.x; s += q.y;
        }
        r = m / s;
    }
#pragma unroll
    for (int off = 32; off > 0; off >>= 1) r += __shfl_down(r, off);
    if (t == 0) out[0] = r * (1.0f / 32.0f);
}

extern "C" void kernel_launch(void* const* d_in, const int* in_sizes, int n_in,
                              void* d_out, int out_size, void* d_ws,
                              size_t ws_size, hipStream_t stream) {
    const float* img = (const float*)d_in[0];
    float* out = (float*)d_out;

    float2* buf = (float2*)d_ws;               // [32][257][512] ~ 33.7MB
    const size_t buf_bytes = (size_t)32 * NCOL * N * sizeof(float2);
    float2* part = (float2*)((char*)d_ws + buf_bytes);  // [32][257] pairs

    dim3 g1(N / 32, 32);                       // 16 row-tiles x 32 images
    k_gray_rowfft<<<g1, 512, 0, stream>>>(img, buf);

    dim3 g2((NCOL + 7) / 8, 32);               // 33 col-groups x 32 images
    k_colfft_reduce<<<g2, 256, 0, stream>>>(buf, part);

    k_final<<<1, 64, 0, stream>>>(part, out);
}

// Round 11
// 178.679 us; speedup vs baseline: 1.0448x; 1.0448x over previous
//
#include <hip/hip_runtime.h>
#include <math.h>

#define N 512
#define NPAD(i) ((i) + ((i) >> 5))
#define FSZ 532
#define NCOL 257           // Hermitian: columns v = 0..256 only
#define NG2 17             // K2 column-groups per image (17*16 = 272 >= 257)
// mask: (u-256)^2 + (v-256)^2 <= 51.2^2 (integer dist^2 exact in fp32)
#define RAD2 2621.44f
#define SQ2H 0.70710678f

// ---------------------------------------------------------------------------
// In-register 8-point DFT, natural order in/out. (R8 verbatim)
// ---------------------------------------------------------------------------
__device__ __forceinline__ void dft8(float (&xr)[8], float (&xi)[8]) {
    float e0r = xr[0] + xr[4], e0i = xi[0] + xi[4];
    float e1r = xr[0] - xr[4], e1i = xi[0] - xi[4];
    float e2r = xr[2] + xr[6], e2i = xi[2] + xi[6];
    float e3r = xr[2] - xr[6], e3i = xi[2] - xi[6];
    float E0r = e0r + e2r, E0i = e0i + e2i;
    float E2r = e0r - e2r, E2i = e0i - e2i;
    float E1r = e1r + e3i, E1i = e1i - e3r;
    float E3r = e1r - e3i, E3i = e1i + e3r;
    float o0r = xr[1] + xr[5], o0i = xi[1] + xi[5];
    float o1r = xr[1] - xr[5], o1i = xi[1] - xi[5];
    float o2r = xr[3] + xr[7], o2i = xi[3] + xi[7];
    float o3r = xr[3] - xr[7], o3i = xi[3] - xi[7];
    float O0r = o0r + o2r, O0i = o0i + o2i;
    float O2r = o0r - o2r, O2i = o0i - o2i;
    float O1r = o1r + o3i, O1i = o1i - o3r;
    float O3r = o1r - o3i, O3i = o1i + o3r;
    float t1r = SQ2H * (O1r + O1i), t1i = SQ2H * (O1i - O1r);
    float t2r = O2i,                t2i = -O2r;
    float t3r = SQ2H * (O3i - O3r), t3i = -SQ2H * (O3r + O3i);
    xr[0] = E0r + O0r; xi[0] = E0i + O0i;
    xr[4] = E0r - O0r; xi[4] = E0i - O0i;
    xr[1] = E1r + t1r; xi[1] = E1i + t1i;
    xr[5] = E1r - t1r; xi[5] = E1i - t1i;
    xr[2] = E2r + t2r; xi[2] = E2i + t2i;
    xr[6] = E2r - t2r; xi[6] = E2i - t2i;
    xr[3] = E3r + t3r; xi[3] = E3i + t3i;
    xr[7] = E3r - t3r; xi[7] = E3i - t3i;
}

// ---------------------------------------------------------------------------
// FOUR interleaved wave-level 512-pt FFTs (x4 ILP — extends R6's winning x2).
// Shared twiddles; R8-style immediate consume per (m,k) — no forced batching.
// Lane l, reg k holds x[8*l + k] in; out: reg t holds X[br6(l) + 64*t].
// ---------------------------------------------------------------------------
__device__ __forceinline__ void fft512_x4(float (&zr)[4][8], float (&zi)[4][8],
                                          int l) {
#pragma unroll
    for (int half = 32; half >= 1; half >>= 1) {
        const int j = l & (half - 1);
        const float f = (float)j * (0.5f / (float)half);   // revolutions
        const float c = __builtin_amdgcn_cosf(f);
        const float s = __builtin_amdgcn_sinf(f);
        const bool up = (l & half) != 0;
        const float sgn = up ? -1.0f : 1.0f;
        const float wc  = up ? c : 1.0f;
        const float ws  = up ? s : 0.0f;
#pragma unroll
        for (int m = 0; m < 4; ++m) {
#pragma unroll
            for (int k = 0; k < 8; ++k) {
                float pr = __shfl_xor(zr[m][k], half);
                float pi = __shfl_xor(zi[m][k], half);
                float tr = fmaf(sgn, zr[m][k], pr);
                float ti = fmaf(sgn, zi[m][k], pi);
                zr[m][k] = tr * wc + ti * ws;
                zi[m][k] = ti * wc - tr * ws;
            }
        }
    }
    const int w = __brev((unsigned)l) >> 26;
#pragma unroll
    for (int k = 1; k < 8; ++k) {
        const float f = (float)(k * w) * (1.0f / 512.0f);
        const float c = __builtin_amdgcn_cosf(f);
        const float s = __builtin_amdgcn_sinf(f);
#pragma unroll
        for (int m = 0; m < 4; ++m) {
            float tr = zr[m][k] * c + zi[m][k] * s;
            float ti = zi[m][k] * c - zr[m][k] * s;
            zr[m][k] = tr; zi[m][k] = ti;
        }
    }
#pragma unroll
    for (int m = 0; m < 4; ++m) dft8(zr[m], zi[m]);
}

// ---------------------------------------------------------------------------
// K1: grayscale + 4 packed row-pair FFTs per wave + Hermitian unpack +
// transposed write. 256 thr = 4 waves = 32 rows/block (same tile as R8,
// half the waves, double the ILP). Output buf[b][v][h], v=0..256.
// ---------------------------------------------------------------------------
__global__ __launch_bounds__(256) void k_gray_rowfft(
    const float* __restrict__ img, float2* __restrict__ buf) {
    __shared__ float sr[16][FSZ], si[16][FSZ];
    const int t = threadIdx.x, wv = t >> 6, l = t & 63;
    const int b = blockIdx.y, tile = blockIdx.x;
    const size_t plane = (size_t)N * N;
    const float* base = img + (size_t)b * 3 * plane;
    const int r0 = tile * 32 + 8 * wv;         // this wave: rows r0..r0+7

    const float inv3 = 1.0f / 3.0f;
    float zr[4][8], zi[4][8];
#pragma unroll
    for (int m = 0; m < 4; ++m) {              // pair m: rows r0+2m, r0+2m+1
        const float* pe = base + (size_t)(r0 + 2 * m) * N;
        const float* po = pe + N;
        const float4* c0e = (const float4*)pe;
        const float4* c1e = (const float4*)(pe + plane);
        const float4* c2e = (const float4*)(pe + 2 * plane);
        const float4* c0o = (const float4*)po;
        const float4* c1o = (const float4*)(po + plane);
        const float4* c2o = (const float4*)(po + 2 * plane);
#pragma unroll
        for (int q = 0; q < 2; ++q) {
            int idx = 2 * l + q;
            float4 a = c0e[idx], bb = c1e[idx], c = c2e[idx];
            float4 d = c0o[idx], e = c1o[idx], g = c2o[idx];
            zr[m][4 * q + 0] = (a.x + bb.x + c.x) * inv3;
            zr[m][4 * q + 1] = (a.y + bb.y + c.y) * inv3;
            zr[m][4 * q + 2] = (a.z + bb.z + c.z) * inv3;
            zr[m][4 * q + 3] = (a.w + bb.w + c.w) * inv3;
            zi[m][4 * q + 0] = (d.x + e.x + g.x) * inv3;
            zi[m][4 * q + 1] = (d.y + e.y + g.y) * inv3;
            zi[m][4 * q + 2] = (d.z + e.z + g.z) * inv3;
            zi[m][4 * q + 3] = (d.w + e.w + g.w) * inv3;
        }
    }

    fft512_x4(zr, zi, l);

    // park packed spectra at natural index u = br6(l) + 64*k; slab = pair
    const int w = __brev((unsigned)l) >> 26;
#pragma unroll
    for (int m = 0; m < 4; ++m) {
        const int slab = 4 * wv + m;           // local pair index = 2 rows
#pragma unroll
        for (int k = 0; k < 8; ++k) {
            int u = w + 64 * k;
            sr[slab][NPAD(u)] = zr[m][k];
            si[slab][NPAD(u)] = zi[m][k];
        }
    }
    __syncthreads();

    // unpack F_even/F_odd; lane emits both parities of pair p = t&15 as one
    // float4 (columns h2, h2+1 of the 32-row tile) for 17 v-slices.
    const int p = t & 15;
    const int h2 = 2 * p;
    const int slot = t >> 4;                   // 0..15
    float2* ob = buf + (size_t)b * NCOL * N;
#pragma unroll
    for (int it = 0; it < 17; ++it) {
        int v = slot + 16 * it;
        if (v < NCOL) {
            int vn = (N - v) & (N - 1);
            float Zr  = sr[p][NPAD(v)],  Zi  = si[p][NPAD(v)];
            float Zr2 = sr[p][NPAD(vn)], Zi2 = si[p][NPAD(vn)];
            float4 o;
            o.x = 0.5f * (Zr + Zr2);           // F_even.re
            o.y = 0.5f * (Zi - Zi2);           // F_even.im
            o.z = 0.5f * (Zi + Zi2);           // F_odd.re
            o.w = 0.5f * (Zr2 - Zr);           // F_odd.im
            *(float4*)(&ob[(size_t)v * N + tile * 32 + h2]) = o;
        }
    }
}

// ---------------------------------------------------------------------------
// K2: 4 column FFTs per wave + masked/total reduction with Hermitian weights
// folded in. No atomics: one partial pair stored per block. 256 thr = 16 cols.
// ---------------------------------------------------------------------------
__global__ __launch_bounds__(256) void k_colfft_reduce(
    const float2* __restrict__ buf, float2* __restrict__ part) {
    __shared__ float red[8];
    const int t = threadIdx.x, wv = t >> 6, l = t & 63;
    const int b = blockIdx.y;
    const int vb = blockIdx.x * 16 + 4 * wv;   // this wave: cols vb..vb+3

    float zr[4][8], zi[4][8];
#pragma unroll
    for (int m = 0; m < 4; ++m) {
        const int v = vb + m;
        const int cc = v > 256 ? 256 : v;      // clamp dummies (weight 0)
        const float4* col = (const float4*)(buf + ((size_t)b * NCOL + cc) * N);
#pragma unroll
        for (int q = 0; q < 4; ++q) {
            float4 z = col[4 * l + q];         // complex 8l+2q, 8l+2q+1
            zr[m][2 * q]     = z.x; zi[m][2 * q]     = z.y;
            zr[m][2 * q + 1] = z.z; zi[m][2 * q + 1] = z.w;
        }
    }

    fft512_x4(zr, zi, l);

    const int w = __brev((unsigned)l) >> 26;
    float msum = 0.0f, tsum = 0.0f;
#pragma unroll
    for (int m = 0; m < 4; ++m) {
        const int v = vb + m;
        const float wcol = (v == 0 || v == 256) ? 1.0f
                                                : (v < 256 ? 2.0f : 0.0f);
        const float dx = (float)((v > 256 ? 256 : v) - 256);
        const float dx2 = dx * dx;
        float mm = 0.0f, tt = 0.0f;
#pragma unroll
        for (int k = 0; k < 8; ++k) {
            int u = w + 64 * k;
            float mag = sqrtf(zr[m][k] * zr[m][k] + zi[m][k] * zi[m][k]);
            tt += mag;
            float dy = (float)(u - 256);
            if (dy * dy + dx2 <= RAD2) mm += mag;
        }
        msum = fmaf(wcol, mm, msum);
        tsum = fmaf(wcol, tt, tsum);
    }
#pragma unroll
    for (int off = 32; off > 0; off >>= 1) {
        msum += __shfl_down(msum, off);
        tsum += __shfl_down(tsum, off);
    }
    if (l == 0) { red[wv * 2] = msum; red[wv * 2 + 1] = tsum; }
    __syncthreads();
    if (t == 0) {
        float m = red[0] + red[2] + red[4] + red[6];
        float s = red[1] + red[3] + red[5] + red[7];
        part[blockIdx.x * 32 + b] = make_float2(m, s);   // plain store
    }
}

// K3: reduce 17 partials per image, then mean of ratios.
__global__ void k_final(const float2* __restrict__ part,
                        float* __restrict__ out) {
    int t = threadIdx.x;                       // 64 threads
    float r = 0.0f;
    if (t < 32) {
        float m = 0.0f, s = 0.0f;
#pragma unroll
        for (int g = 0; g < NG2; ++g) {
            float2 p = part[g * 32 + t];
            m += p.x; s += p.y;
        }
        r = m / s;
    }
#pragma unroll
    for (int off = 32; off > 0; off >>= 1) r += __shfl_down(r, off);
    if (t == 0) out[0] = r * (1.0f / 32.0f);
}

extern "C" void kernel_launch(void* const* d_in, const int* in_sizes, int n_in,
                              void* d_out, int out_size, void* d_ws,
                              size_t ws_size, hipStream_t stream) {
    const float* img = (const float*)d_in[0];
    float* out = (float*)d_out;

    float2* buf = (float2*)d_ws;               // [32][257][512] ~ 33.7MB
    const size_t buf_bytes = (size_t)32 * NCOL * N * sizeof(float2);
    float2* part = (float2*)((char*)d_ws + buf_bytes);  // [17][32] pairs

    dim3 g1(N / 32, 32);                       // 16 row-tiles x 32 images
    k_gray_rowfft<<<g1, 256, 0, stream>>>(img, buf);

    dim3 g2(NG2, 32);                          // 17 col-groups x 32 images
    k_colfft_reduce<<<g2, 256, 0, stream>>>(buf, part);

    k_final<<<1, 64, 0, stream>>>(part, out);
}

// Round 12
// 169.380 us; speedup vs baseline: 1.1022x; 1.0549x over previous
//
#include <hip/hip_runtime.h>
#include <math.h>

#define N 512
#define NPAD(i) ((i) + ((i) >> 5))
#define FSZ 532
#define NCOL 257           // Hermitian: columns v = 0..256 only
#define NG2 33             // K2 column-groups per image (33*8 = 264 >= 257)
// mask: (u-256)^2 + (v-256)^2 <= 51.2^2 (integer dist^2 exact in fp32)
#define RAD2 2621.44f
#define SQ2H 0.70710678f

// ---------------------------------------------------------------------------
// In-register 8-point DFT, natural order in/out. (R8 verbatim)
// ---------------------------------------------------------------------------
__device__ __forceinline__ void dft8(float (&xr)[8], float (&xi)[8]) {
    float e0r = xr[0] + xr[4], e0i = xi[0] + xi[4];
    float e1r = xr[0] - xr[4], e1i = xi[0] - xi[4];
    float e2r = xr[2] + xr[6], e2i = xi[2] + xi[6];
    float e3r = xr[2] - xr[6], e3i = xi[2] - xi[6];
    float E0r = e0r + e2r, E0i = e0i + e2i;
    float E2r = e0r - e2r, E2i = e0i - e2i;
    float E1r = e1r + e3i, E1i = e1i - e3r;
    float E3r = e1r - e3i, E3i = e1i + e3r;
    float o0r = xr[1] + xr[5], o0i = xi[1] + xi[5];
    float o1r = xr[1] - xr[5], o1i = xi[1] - xi[5];
    float o2r = xr[3] + xr[7], o2i = xi[3] + xi[7];
    float o3r = xr[3] - xr[7], o3i = xi[3] - xi[7];
    float O0r = o0r + o2r, O0i = o0i + o2i;
    float O2r = o0r - o2r, O2i = o0i - o2i;
    float O1r = o1r + o3i, O1i = o1i - o3r;
    float O3r = o1r - o3i, O3i = o1i + o3r;
    float t1r = SQ2H * (O1r + O1i), t1i = SQ2H * (O1i - O1r);
    float t2r = O2i,                t2i = -O2r;
    float t3r = SQ2H * (O3i - O3r), t3i = -SQ2H * (O3r + O3i);
    xr[0] = E0r + O0r; xi[0] = E0i + O0i;
    xr[4] = E0r - O0r; xi[4] = E0i - O0i;
    xr[1] = E1r + t1r; xi[1] = E1i + t1i;
    xr[5] = E1r - t1r; xi[5] = E1i - t1i;
    xr[2] = E2r + t2r; xi[2] = E2i + t2i;
    xr[6] = E2r - t2r; xi[6] = E2i - t2i;
    xr[3] = E3r + t3r; xi[3] = E3i + t3i;
    xr[7] = E3r - t3r; xi[7] = E3i - t3i;
}

// ---------------------------------------------------------------------------
// TWO interleaved wave-level 512-pt FFTs (R8 verbatim).
// Lane l, reg k holds x[8*l + k] in; out: reg t holds X[br6(l) + 64*t].
// ---------------------------------------------------------------------------
__device__ __forceinline__ void fft512_x2(float (&ar)[8], float (&ai)[8],
                                          float (&br)[8], float (&bi)[8],
                                          int l) {
#pragma unroll
    for (int half = 32; half >= 1; half >>= 1) {
        const int j = l & (half - 1);
        const float f = (float)j * (0.5f / (float)half);   // revolutions
        const float c = __builtin_amdgcn_cosf(f);
        const float s = __builtin_amdgcn_sinf(f);
        const bool up = (l & half) != 0;
        const float sgn = up ? -1.0f : 1.0f;
        const float wc  = up ? c : 1.0f;
        const float ws  = up ? s : 0.0f;
#pragma unroll
        for (int k = 0; k < 8; ++k) {
            float pr = __shfl_xor(ar[k], half);
            float pi = __shfl_xor(ai[k], half);
            float qr = __shfl_xor(br[k], half);
            float qi = __shfl_xor(bi[k], half);
            float tr = fmaf(sgn, ar[k], pr);
            float ti = fmaf(sgn, ai[k], pi);
            float ur = fmaf(sgn, br[k], qr);
            float ui = fmaf(sgn, bi[k], qi);
            ar[k] = tr * wc + ti * ws;
            ai[k] = ti * wc - tr * ws;
            br[k] = ur * wc + ui * ws;
            bi[k] = ui * wc - ur * ws;
        }
    }
    const int w = __brev((unsigned)l) >> 26;
#pragma unroll
    for (int k = 1; k < 8; ++k) {
        const float f = (float)(k * w) * (1.0f / 512.0f);
        const float c = __builtin_amdgcn_cosf(f);
        const float s = __builtin_amdgcn_sinf(f);
        float tr = ar[k] * c + ai[k] * s;
        float ti = ai[k] * c - ar[k] * s;
        ar[k] = tr; ai[k] = ti;
        float ur = br[k] * c + bi[k] * s;
        float ui = bi[k] * c - br[k] * s;
        br[k] = ur; bi[k] = ui;
    }
    dft8(ar, ai);
    dft8(br, bi);
}

// ---------------------------------------------------------------------------
// K1: grayscale + 2 packed row-pair FFTs per wave + Hermitian unpack +
// transposed write. 512 thr = 8 waves = 32 rows. (R8 verbatim)
// ---------------------------------------------------------------------------
__global__ __launch_bounds__(512) void k_gray_rowfft(
    const float* __restrict__ img, float2* __restrict__ buf) {
    __shared__ float sr[16][FSZ], si[16][FSZ];
    const int t = threadIdx.x, wv = t >> 6, l = t & 63;
    const int b = blockIdx.y, tile = blockIdx.x;
    const size_t plane = (size_t)N * N;
    const float* base = img + (size_t)b * 3 * plane;
    const int r0 = tile * 32 + 4 * wv;

    const float inv3 = 1.0f / 3.0f;
    auto loadgray = [&](const float* p, float (&g)[8]) {
        const float4* c0 = (const float4*)p;
        const float4* c1 = (const float4*)(p + plane);
        const float4* c2 = (const float4*)(p + 2 * plane);
#pragma unroll
        for (int q = 0; q < 2; ++q) {
            float4 a = c0[2 * l + q], bb = c1[2 * l + q], c = c2[2 * l + q];
            g[4 * q + 0] = (a.x + bb.x + c.x) * inv3;
            g[4 * q + 1] = (a.y + bb.y + c.y) * inv3;
            g[4 * q + 2] = (a.z + bb.z + c.z) * inv3;
            g[4 * q + 3] = (a.w + bb.w + c.w) * inv3;
        }
    };

    float arr[8], ari[8], brr[8], bri[8];
    loadgray(base + (size_t)(r0 + 0) * N, arr);
    loadgray(base + (size_t)(r0 + 1) * N, ari);
    loadgray(base + (size_t)(r0 + 2) * N, brr);
    loadgray(base + (size_t)(r0 + 3) * N, bri);

    fft512_x2(arr, ari, brr, bri, l);

    const int w = __brev((unsigned)l) >> 26;
    const int sA = 2 * wv, sB = 2 * wv + 1;
#pragma unroll
    for (int k = 0; k < 8; ++k) {
        int u = w + 64 * k;
        sr[sA][NPAD(u)] = arr[k]; si[sA][NPAD(u)] = ari[k];
        sr[sB][NPAD(u)] = brr[k]; si[sB][NPAD(u)] = bri[k];
    }
    __syncthreads();

    const int p = t & 15;
    const int h2 = 2 * p;
    const int slot = t >> 4;
    float2* ob = buf + (size_t)b * NCOL * N;
#pragma unroll
    for (int it = 0; it < 9; ++it) {
        int v = slot + 32 * it;
        if (v < NCOL) {
            int vn = (N - v) & (N - 1);
            float Zr  = sr[p][NPAD(v)],  Zi  = si[p][NPAD(v)];
            float Zr2 = sr[p][NPAD(vn)], Zi2 = si[p][NPAD(vn)];
            float4 o;
            o.x = 0.5f * (Zr + Zr2);
            o.y = 0.5f * (Zi - Zi2);
            o.z = 0.5f * (Zi + Zi2);
            o.w = 0.5f * (Zr2 - Zr);
            *(float4*)(&ob[(size_t)v * N + tile * 32 + h2]) = o;
        }
    }
}

// ---------------------------------------------------------------------------
// K2: 2 column FFTs per wave + masked/total partial sums. XCD-AWARE 1D GRID:
// block id -> xcd = id&7 (round-robin dispatch), image b = xcd + 8*(slot/33),
// group g = slot%33 — all 33 column-blocks of an image land on ONE XCD, so
// its 1.05 MB slice stays L2-resident (4 images x 1.05 MB ~ one 4 MB L2).
// Mapping is a locality heuristic only; any dispatch order stays correct.
// ---------------------------------------------------------------------------
__global__ __launch_bounds__(256) void k_colfft_reduce(
    const float2* __restrict__ buf, float2* __restrict__ part) {
    __shared__ float red[8];
    const int t = threadIdx.x, wv = t >> 6, l = t & 63;

    const unsigned id = blockIdx.x;            // 0..1055
    const int xcd  = (int)(id & 7u);
    const int slot = (int)(id >> 3);           // 0..131
    const int b = xcd + 8 * (slot / NG2);      // image 0..31
    const int g = slot % NG2;                  // column group 0..32

    const int v0 = g * 8 + 2 * wv;
    const int v1 = v0 + 1;
    const int c0 = v0 > 256 ? 256 : v0;
    const int c1 = v1 > 256 ? 256 : v1;

    const float4* colA = (const float4*)(buf + ((size_t)b * NCOL + c0) * N);
    const float4* colB = (const float4*)(buf + ((size_t)b * NCOL + c1) * N);
    float arr[8], ari[8], brr[8], bri[8];
#pragma unroll
    for (int q = 0; q < 4; ++q) {
        float4 zA = colA[4 * l + q];
        float4 zB = colB[4 * l + q];
        arr[2 * q] = zA.x; ari[2 * q] = zA.y;
        arr[2 * q + 1] = zA.z; ari[2 * q + 1] = zA.w;
        brr[2 * q] = zB.x; bri[2 * q] = zB.y;
        brr[2 * q + 1] = zB.z; bri[2 * q + 1] = zB.w;
    }

    fft512_x2(arr, ari, brr, bri, l);

    const float wA = (v0 == 0 || v0 == 256) ? 1.0f : (v0 < 256 ? 2.0f : 0.0f);
    const float wB = (v1 == 256) ? 1.0f : (v1 < 256 ? 2.0f : 0.0f);
    const float dxA = (float)(c0 - 256), dxA2 = dxA * dxA;
    const float dxB = (float)(c1 - 256), dxB2 = dxB * dxB;
    const int w = __brev((unsigned)l) >> 26;
    float msum = 0.0f, tsum = 0.0f;
#pragma unroll
    for (int k = 0; k < 8; ++k) {
        int u = w + 64 * k;
        float dy = (float)(u - 256);
        float dy2 = dy * dy;
        float magA = sqrtf(arr[k] * arr[k] + ari[k] * ari[k]) * wA;
        float magB = sqrtf(brr[k] * brr[k] + bri[k] * bri[k]) * wB;
        tsum += magA + magB;
        float m = 0.0f;
        if (dy2 + dxA2 <= RAD2) m += magA;
        if (dy2 + dxB2 <= RAD2) m += magB;
        msum += m;
    }
#pragma unroll
    for (int off = 32; off > 0; off >>= 1) {
        msum += __shfl_down(msum, off);
        tsum += __shfl_down(tsum, off);
    }
    if (l == 0) { red[wv * 2] = msum; red[wv * 2 + 1] = tsum; }
    __syncthreads();
    if (t == 0) {
        float m = red[0] + red[2] + red[4] + red[6];
        float s = red[1] + red[3] + red[5] + red[7];
        part[g * 32 + b] = make_float2(m, s);  // plain store
    }
}

// K3: reduce 33 partials per image, then mean of ratios. (R8 verbatim)
__global__ void k_final(const float2* __restrict__ part,
                        float* __restrict__ out) {
    int t = threadIdx.x;                       // 64 threads
    float r = 0.0f;
    if (t < 32) {
        float m = 0.0f, s = 0.0f;
#pragma unroll
        for (int g = 0; g < NG2; ++g) {
            float2 p = part[g * 32 + t];
            m += p.x; s += p.y;
        }
        r = m / s;
    }
#pragma unroll
    for (int off = 32; off > 0; off >>= 1) r += __shfl_down(r, off);
    if (t == 0) out[0] = r * (1.0f / 32.0f);
}

extern "C" void kernel_launch(void* const* d_in, const int* in_sizes, int n_in,
                              void* d_out, int out_size, void* d_ws,
                              size_t ws_size, hipStream_t stream) {
    const float* img = (const float*)d_in[0];
    float* out = (float*)d_out;

    float2* buf = (float2*)d_ws;               // [32][257][512] ~ 33.7MB
    const size_t buf_bytes = (size_t)32 * NCOL * N * sizeof(float2);
    float2* part = (float2*)((char*)d_ws + buf_bytes);  // [33][32] pairs

    dim3 g1(N / 32, 32);                       // 16 row-tiles x 32 images
    k_gray_rowfft<<<g1, 512, 0, stream>>>(img, buf);

    k_colfft_reduce<<<dim3(8 * 132), 256, 0, stream>>>(buf, part);

    k_final<<<1, 64, 0, stream>>>(part, out);
}

// Round 13
// 167.499 us; speedup vs baseline: 1.1145x; 1.0112x over previous
//
#include <hip/hip_runtime.h>
#include <math.h>

#define N 512
#define NPAD(i) ((i) + ((i) >> 5))
#define FSZ 532
#define NCOL 257           // Hermitian: columns v = 0..256 only
#define NG2 33             // K2 column-groups per image (33*8 = 264 >= 257)
// mask: (u-256)^2 + (v-256)^2 <= 51.2^2 (integer dist^2 exact in fp32)
#define RAD2 2621.44f
#define SQ2H 0.70710678f

// ---------------------------------------------------------------------------
// Cross-lane primitives on the VALU pipe (gfx950):
//  - v_permlane32_swap_b32 / v_permlane16_swap_b32: swap half-rows between
//    two VGPRs (xor-32 / xor-16 exchange without LDS).
//  - DPP quad_perm: xor-1 / xor-2 within quads.
// xor-8 / xor-4 stay on LDS as immediate-pattern ds_swizzle.
// ---------------------------------------------------------------------------
__device__ __forceinline__ void plswap32(float& x, float& y) {
    asm volatile("s_nop 1\n\tv_permlane32_swap_b32 %0, %1\n\ts_nop 1"
                 : "+v"(x), "+v"(y));
}
__device__ __forceinline__ void plswap16(float& x, float& y) {
    asm volatile("s_nop 1\n\tv_permlane16_swap_b32 %0, %1\n\ts_nop 1"
                 : "+v"(x), "+v"(y));
}
template <int PAT>
__device__ __forceinline__ float ds_swz(float v) {
    return __int_as_float(
        __builtin_amdgcn_ds_swizzle(__float_as_int(v), PAT));
}
template <int CTRL>
__device__ __forceinline__ float dppq(float v) {
    return __int_as_float(__builtin_amdgcn_update_dpp(
        0, __float_as_int(v), CTRL, 0xF, 0xF, false));
}

// ---------------------------------------------------------------------------
// In-register 8-point DFT, natural order in/out. (R8 verbatim)
// ---------------------------------------------------------------------------
__device__ __forceinline__ void dft8(float (&xr)[8], float (&xi)[8]) {
    float e0r = xr[0] + xr[4], e0i = xi[0] + xi[4];
    float e1r = xr[0] - xr[4], e1i = xi[0] - xi[4];
    float e2r = xr[2] + xr[6], e2i = xi[2] + xi[6];
    float e3r = xr[2] - xr[6], e3i = xi[2] - xi[6];
    float E0r = e0r + e2r, E0i = e0i + e2i;
    float E2r = e0r - e2r, E2i = e0i - e2i;
    float E1r = e1r + e3i, E1i = e1i - e3r;
    float E3r = e1r - e3i, E3i = e1i + e3r;
    float o0r = xr[1] + xr[5], o0i = xi[1] + xi[5];
    float o1r = xr[1] - xr[5], o1i = xi[1] - xi[5];
    float o2r = xr[3] + xr[7], o2i = xi[3] + xi[7];
    float o3r = xr[3] - xr[7], o3i = xi[3] - xi[7];
    float O0r = o0r + o2r, O0i = o0i + o2i;
    float O2r = o0r - o2r, O2i = o0i - o2i;
    float O1r = o1r + o3i, O1i = o1i - o3r;
    float O3r = o1r - o3i, O3i = o1i + o3r;
    float t1r = SQ2H * (O1r + O1i), t1i = SQ2H * (O1i - O1r);
    float t2r = O2i,                t2i = -O2r;
    float t3r = SQ2H * (O3i - O3r), t3i = -SQ2H * (O3r + O3i);
    xr[0] = E0r + O0r; xi[0] = E0i + O0i;
    xr[4] = E0r - O0r; xi[4] = E0i - O0i;
    xr[1] = E1r + t1r; xi[1] = E1i + t1i;
    xr[5] = E1r - t1r; xi[5] = E1i - t1i;
    xr[2] = E2r + t2r; xi[2] = E2i + t2i;
    xr[6] = E2r - t2r; xi[6] = E2i - t2i;
    xr[3] = E3r + t3r; xi[3] = E3i + t3i;
    xr[7] = E3r - t3r; xi[7] = E3i - t3i;
}

// ---------------------------------------------------------------------------
// TWO interleaved wave-level 512-pt FFTs. Same butterfly network/output
// permutation as R8 (out: reg t holds X[br6(l) + 64*t]); only the exchange
// instructions changed: xor32/16 -> permlane swap (VALU), xor8/4 ->
// ds_swizzle imm, xor2/1 -> DPP quad_perm (VALU).
// ---------------------------------------------------------------------------
__device__ __forceinline__ void fft512_x2(float (&ar)[8], float (&ai)[8],
                                          float (&br)[8], float (&bi)[8],
                                          int l) {
    // ---- stage 32: permlane32_swap ----
    {
        const int j = l & 31;
        const float f = (float)j * (1.0f / 64.0f);
        const float c = __builtin_amdgcn_cosf(f);
        const float s = __builtin_amdgcn_sinf(f);
        const bool up = (l & 32) != 0;
        const float sgn = up ? -1.0f : 1.0f;
        const float wc  = up ? c : 1.0f;
        const float ws  = up ? s : 0.0f;
#pragma unroll
        for (int k = 0; k < 8; ++k) {
            float xr = ar[k], yr = ar[k], xi = ai[k], yi = ai[k];
            float Xr = br[k], Yr = br[k], Xi = bi[k], Yi = bi[k];
            plswap32(xr, yr); plswap32(xi, yi);
            plswap32(Xr, Yr); plswap32(Xi, Yi);
            float tr = fmaf(sgn, yr, xr);
            float ti = fmaf(sgn, yi, xi);
            float ur = fmaf(sgn, Yr, Xr);
            float ui = fmaf(sgn, Yi, Xi);
            ar[k] = tr * wc + ti * ws;
            ai[k] = ti * wc - tr * ws;
            br[k] = ur * wc + ui * ws;
            bi[k] = ui * wc - ur * ws;
        }
    }
    // ---- stage 16: permlane16_swap ----
    {
        const int j = l & 15;
        const float f = (float)j * (1.0f / 32.0f);
        const float c = __builtin_amdgcn_cosf(f);
        const float s = __builtin_amdgcn_sinf(f);
        const bool up = (l & 16) != 0;
        const float sgn = up ? -1.0f : 1.0f;
        const float wc  = up ? c : 1.0f;
        const float ws  = up ? s : 0.0f;
#pragma unroll
        for (int k = 0; k < 8; ++k) {
            float xr = ar[k], yr = ar[k], xi = ai[k], yi = ai[k];
            float Xr = br[k], Yr = br[k], Xi = bi[k], Yi = bi[k];
            plswap16(xr, yr); plswap16(xi, yi);
            plswap16(Xr, Yr); plswap16(Xi, Yi);
            float tr = fmaf(sgn, yr, xr);
            float ti = fmaf(sgn, yi, xi);
            float ur = fmaf(sgn, Yr, Xr);
            float ui = fmaf(sgn, Yi, Xi);
            ar[k] = tr * wc + ti * ws;
            ai[k] = ti * wc - tr * ws;
            br[k] = ur * wc + ui * ws;
            bi[k] = ui * wc - ur * ws;
        }
    }
    // ---- stages 8, 4: ds_swizzle imm (xor within 32-lane groups) ----
    {
        const int j = l & 7;
        const float f = (float)j * (1.0f / 16.0f);
        const float c = __builtin_amdgcn_cosf(f);
        const float s = __builtin_amdgcn_sinf(f);
        const bool up = (l & 8) != 0;
        const float sgn = up ? -1.0f : 1.0f;
        const float wc  = up ? c : 1.0f;
        const float ws  = up ? s : 0.0f;
#pragma unroll
        for (int k = 0; k < 8; ++k) {
            float pr = ds_swz<0x201F>(ar[k]);
            float pi = ds_swz<0x201F>(ai[k]);
            float qr = ds_swz<0x201F>(br[k]);
            float qi = ds_swz<0x201F>(bi[k]);
            float tr = fmaf(sgn, ar[k], pr);
            float ti = fmaf(sgn, ai[k], pi);
            float ur = fmaf(sgn, br[k], qr);
            float ui = fmaf(sgn, bi[k], qi);
            ar[k] = tr * wc + ti * ws;
            ai[k] = ti * wc - tr * ws;
            br[k] = ur * wc + ui * ws;
            bi[k] = ui * wc - ur * ws;
        }
    }
    {
        const int j = l & 3;
        const float f = (float)j * (1.0f / 8.0f);
        const float c = __builtin_amdgcn_cosf(f);
        const float s = __builtin_amdgcn_sinf(f);
        const bool up = (l & 4) != 0;
        const float sgn = up ? -1.0f : 1.0f;
        const float wc  = up ? c : 1.0f;
        const float ws  = up ? s : 0.0f;
#pragma unroll
        for (int k = 0; k < 8; ++k) {
            float pr = ds_swz<0x101F>(ar[k]);
            float pi = ds_swz<0x101F>(ai[k]);
            float qr = ds_swz<0x101F>(br[k]);
            float qi = ds_swz<0x101F>(bi[k]);
            float tr = fmaf(sgn, ar[k], pr);
            float ti = fmaf(sgn, ai[k], pi);
            float ur = fmaf(sgn, br[k], qr);
            float ui = fmaf(sgn, bi[k], qi);
            ar[k] = tr * wc + ti * ws;
            ai[k] = ti * wc - tr * ws;
            br[k] = ur * wc + ui * ws;
            bi[k] = ui * wc - ur * ws;
        }
    }
    // ---- stage 2: DPP quad_perm [2,3,0,1] (xor2) ----
    {
        const int j = l & 1;
        const float f = (float)j * 0.25f;
        const float c = __builtin_amdgcn_cosf(f);
        const float s = __builtin_amdgcn_sinf(f);
        const bool up = (l & 2) != 0;
        const float sgn = up ? -1.0f : 1.0f;
        const float wc  = up ? c : 1.0f;
        const float ws  = up ? s : 0.0f;
#pragma unroll
        for (int k = 0; k < 8; ++k) {
            float pr = dppq<0x4E>(ar[k]);
            float pi = dppq<0x4E>(ai[k]);
            float qr = dppq<0x4E>(br[k]);
            float qi = dppq<0x4E>(bi[k]);
            float tr = fmaf(sgn, ar[k], pr);
            float ti = fmaf(sgn, ai[k], pi);
            float ur = fmaf(sgn, br[k], qr);
            float ui = fmaf(sgn, bi[k], qi);
            ar[k] = tr * wc + ti * ws;
            ai[k] = ti * wc - tr * ws;
            br[k] = ur * wc + ui * ws;
            bi[k] = ui * wc - ur * ws;
        }
    }
    // ---- stage 1: DPP quad_perm [1,0,3,2] (xor1); twiddle = 1 ----
    {
        const bool up = (l & 1) != 0;
        const float sgn = up ? -1.0f : 1.0f;
#pragma unroll
        for (int k = 0; k < 8; ++k) {
            float pr = dppq<0xB1>(ar[k]);
            float pi = dppq<0xB1>(ai[k]);
            float qr = dppq<0xB1>(br[k]);
            float qi = dppq<0xB1>(bi[k]);
            ar[k] = fmaf(sgn, ar[k], pr);
            ai[k] = fmaf(sgn, ai[k], pi);
            br[k] = fmaf(sgn, br[k], qr);
            bi[k] = fmaf(sgn, bi[k], qi);
        }
    }
    // ---- per-lane twiddle + in-register DFT8 (unchanged) ----
    const int w = __brev((unsigned)l) >> 26;
#pragma unroll
    for (int k = 1; k < 8; ++k) {
        const float f = (float)(k * w) * (1.0f / 512.0f);
        const float c = __builtin_amdgcn_cosf(f);
        const float s = __builtin_amdgcn_sinf(f);
        float tr = ar[k] * c + ai[k] * s;
        float ti = ai[k] * c - ar[k] * s;
        ar[k] = tr; ai[k] = ti;
        float ur = br[k] * c + bi[k] * s;
        float ui = bi[k] * c - br[k] * s;
        br[k] = ur; bi[k] = ui;
    }
    dft8(ar, ai);
    dft8(br, bi);
}

// ---------------------------------------------------------------------------
// K1: grayscale + 2 packed row-pair FFTs per wave + Hermitian unpack +
// transposed write. 512 thr = 8 waves = 32 rows. (R12 verbatim)
// ---------------------------------------------------------------------------
__global__ __launch_bounds__(512) void k_gray_rowfft(
    const float* __restrict__ img, float2* __restrict__ buf) {
    __shared__ float sr[16][FSZ], si[16][FSZ];
    const int t = threadIdx.x, wv = t >> 6, l = t & 63;
    const int b = blockIdx.y, tile = blockIdx.x;
    const size_t plane = (size_t)N * N;
    const float* base = img + (size_t)b * 3 * plane;
    const int r0 = tile * 32 + 4 * wv;

    const float inv3 = 1.0f / 3.0f;
    auto loadgray = [&](const float* p, float (&g)[8]) {
        const float4* c0 = (const float4*)p;
        const float4* c1 = (const float4*)(p + plane);
        const float4* c2 = (const float4*)(p + 2 * plane);
#pragma unroll
        for (int q = 0; q < 2; ++q) {
            float4 a = c0[2 * l + q], bb = c1[2 * l + q], c = c2[2 * l + q];
            g[4 * q + 0] = (a.x + bb.x + c.x) * inv3;
            g[4 * q + 1] = (a.y + bb.y + c.y) * inv3;
            g[4 * q + 2] = (a.z + bb.z + c.z) * inv3;
            g[4 * q + 3] = (a.w + bb.w + c.w) * inv3;
        }
    };

    float arr[8], ari[8], brr[8], bri[8];
    loadgray(base + (size_t)(r0 + 0) * N, arr);
    loadgray(base + (size_t)(r0 + 1) * N, ari);
    loadgray(base + (size_t)(r0 + 2) * N, brr);
    loadgray(base + (size_t)(r0 + 3) * N, bri);

    fft512_x2(arr, ari, brr, bri, l);

    const int w = __brev((unsigned)l) >> 26;
    const int sA = 2 * wv, sB = 2 * wv + 1;
#pragma unroll
    for (int k = 0; k < 8; ++k) {
        int u = w + 64 * k;
        sr[sA][NPAD(u)] = arr[k]; si[sA][NPAD(u)] = ari[k];
        sr[sB][NPAD(u)] = brr[k]; si[sB][NPAD(u)] = bri[k];
    }
    __syncthreads();

    const int p = t & 15;
    const int h2 = 2 * p;
    const int slot = t >> 4;
    float2* ob = buf + (size_t)b * NCOL * N;
#pragma unroll
    for (int it = 0; it < 9; ++it) {
        int v = slot + 32 * it;
        if (v < NCOL) {
            int vn = (N - v) & (N - 1);
            float Zr  = sr[p][NPAD(v)],  Zi  = si[p][NPAD(v)];
            float Zr2 = sr[p][NPAD(vn)], Zi2 = si[p][NPAD(vn)];
            float4 o;
            o.x = 0.5f * (Zr + Zr2);
            o.y = 0.5f * (Zi - Zi2);
            o.z = 0.5f * (Zi + Zi2);
            o.w = 0.5f * (Zr2 - Zr);
            *(float4*)(&ob[(size_t)v * N + tile * 32 + h2]) = o;
        }
    }
}

// ---------------------------------------------------------------------------
// K2: 2 column FFTs per wave + masked/total partial sums; XCD-aware 1D grid
// (R12 verbatim apart from the shared FFT engine).
// ---------------------------------------------------------------------------
__global__ __launch_bounds__(256) void k_colfft_reduce(
    const float2* __restrict__ buf, float2* __restrict__ part) {
    __shared__ float red[8];
    const int t = threadIdx.x, wv = t >> 6, l = t & 63;

    const unsigned id = blockIdx.x;            // 0..1055
    const int xcd  = (int)(id & 7u);
    const int slot = (int)(id >> 3);           // 0..131
    const int b = xcd + 8 * (slot / NG2);      // image 0..31
    const int g = slot % NG2;                  // column group 0..32

    const int v0 = g * 8 + 2 * wv;
    const int v1 = v0 + 1;
    const int c0 = v0 > 256 ? 256 : v0;
    const int c1 = v1 > 256 ? 256 : v1;

    const float4* colA = (const float4*)(buf + ((size_t)b * NCOL + c0) * N);
    const float4* colB = (const float4*)(buf + ((size_t)b * NCOL + c1) * N);
    float arr[8], ari[8], brr[8], bri[8];
#pragma unroll
    for (int q = 0; q < 4; ++q) {
        float4 zA = colA[4 * l + q];
        float4 zB = colB[4 * l + q];
        arr[2 * q] = zA.x; ari[2 * q] = zA.y;
        arr[2 * q + 1] = zA.z; ari[2 * q + 1] = zA.w;
        brr[2 * q] = zB.x; bri[2 * q] = zB.y;
        brr[2 * q + 1] = zB.z; bri[2 * q + 1] = zB.w;
    }

    fft512_x2(arr, ari, brr, bri, l);

    const float wA = (v0 == 0 || v0 == 256) ? 1.0f : (v0 < 256 ? 2.0f : 0.0f);
    const float wB = (v1 == 256) ? 1.0f : (v1 < 256 ? 2.0f : 0.0f);
    const float dxA = (float)(c0 - 256), dxA2 = dxA * dxA;
    const float dxB = (float)(c1 - 256), dxB2 = dxB * dxB;
    const int w = __brev((unsigned)l) >> 26;
    float msum = 0.0f, tsum = 0.0f;
#pragma unroll
    for (int k = 0; k < 8; ++k) {
        int u = w + 64 * k;
        float dy = (float)(u - 256);
        float dy2 = dy * dy;
        float magA = sqrtf(arr[k] * arr[k] + ari[k] * ari[k]) * wA;
        float magB = sqrtf(brr[k] * brr[k] + bri[k] * bri[k]) * wB;
        tsum += magA + magB;
        float m = 0.0f;
        if (dy2 + dxA2 <= RAD2) m += magA;
        if (dy2 + dxB2 <= RAD2) m += magB;
        msum += m;
    }
#pragma unroll
    for (int off = 32; off > 0; off >>= 1) {
        msum += __shfl_down(msum, off);
        tsum += __shfl_down(tsum, off);
    }
    if (l == 0) { red[wv * 2] = msum; red[wv * 2 + 1] = tsum; }
    __syncthreads();
    if (t == 0) {
        float m = red[0] + red[2] + red[4] + red[6];
        float s = red[1] + red[3] + red[5] + red[7];
        part[g * 32 + b] = make_float2(m, s);  // plain store
    }
}

// K3: reduce 33 partials per image, then mean of ratios. (R12 verbatim)
__global__ void k_final(const float2* __restrict__ part,
                        float* __restrict__ out) {
    int t = threadIdx.x;                       // 64 threads
    float r = 0.0f;
    if (t < 32) {
        float m = 0.0f, s = 0.0f;
#pragma unroll
        for (int g = 0; g < NG2; ++g) {
            float2 p = part[g * 32 + t];
            m += p.x; s += p.y;
        }
        r = m / s;
    }
#pragma unroll
    for (int off = 32; off > 0; off >>= 1) r += __shfl_down(r, off);
    if (t == 0) out[0] = r * (1.0f / 32.0f);
}

extern "C" void kernel_launch(void* const* d_in, const int* in_sizes, int n_in,
                              void* d_out, int out_size, void* d_ws,
                              size_t ws_size, hipStream_t stream) {
    const float* img = (const float*)d_in[0];
    float* out = (float*)d_out;

    float2* buf = (float2*)d_ws;               // [32][257][512] ~ 33.7MB
    const size_t buf_bytes = (size_t)32 * NCOL * N * sizeof(float2);
    float2* part = (float2*)((char*)d_ws + buf_bytes);  // [33][32] pairs

    dim3 g1(N / 32, 32);                       // 16 row-tiles x 32 images
    k_gray_rowfft<<<g1, 512, 0, stream>>>(img, buf);

    k_colfft_reduce<<<dim3(8 * 132), 256, 0, stream>>>(buf, part);

    k_final<<<1, 64, 0, stream>>>(part, out);
}